// Round 3
// baseline (111.335 us; speedup 1.0000x reference)
//
#include <hip/hip_runtime.h>

// Segmented (per-ray) weighted RGB sum over SORTED ray_indices.
// Each lane owns 8 contiguous samples: serial in-register reduce (VALU only),
// then ONE wave-level segmented suffix scan per 512 samples merges per-lane
// tail pieces across lanes. Run boundaries: head piece -> atomic (run end),
// interior complete segments -> atomic (rare), scan-head lanes -> atomic of
// merged tail run. Atomics merge partial runs across waves.

#define SPL 8                    // contiguous samples per lane
#define WAVE_SAMPLES (64 * SPL)  // 512

__global__ __launch_bounds__(256, 6) void integrate_kernel(
    const float* __restrict__ rgb,      // [n, 3]
    const float* __restrict__ w,        // [n, 1]
    const int*   __restrict__ idx,      // [n] sorted
    float*       __restrict__ out,      // [n_rays, 3], pre-zeroed
    int n)
{
    const int lane = threadIdx.x & 63;
    const long long wave  = ((long long)blockIdx.x * blockDim.x + threadIdx.x) >> 6;
    const long long wbase = wave * WAVE_SAMPLES;
    if (wbase >= n) return;             // wave-uniform exit only
    const long long base = wbase + (long long)lane * SPL;

    int   ids[SPL];
    float ws[SPL], sx[SPL], sy[SPL], sz[SPL];

    if (base + SPL <= n) {
        // Vector loads: 32B idx, 32B w, 96B rgb per lane (all 16B-aligned).
        int4   i0 = *(const int4*)(idx + base);
        int4   i1 = *(const int4*)(idx + base + 4);
        float4 w0 = *(const float4*)(w + base);
        float4 w1 = *(const float4*)(w + base + 4);
        const float4* r4 = (const float4*)(rgb + 3 * base);
        float4 r0 = r4[0], r1 = r4[1], r2 = r4[2];
        float4 r3 = r4[3], r4v = r4[4], r5 = r4[5];

        ids[0]=i0.x; ids[1]=i0.y; ids[2]=i0.z; ids[3]=i0.w;
        ids[4]=i1.x; ids[5]=i1.y; ids[6]=i1.z; ids[7]=i1.w;
        ws[0]=w0.x; ws[1]=w0.y; ws[2]=w0.z; ws[3]=w0.w;
        ws[4]=w1.x; ws[5]=w1.y; ws[6]=w1.z; ws[7]=w1.w;
        sx[0]=r0.x;  sy[0]=r0.y;  sz[0]=r0.z;
        sx[1]=r0.w;  sy[1]=r1.x;  sz[1]=r1.y;
        sx[2]=r1.z;  sy[2]=r1.w;  sz[2]=r2.x;
        sx[3]=r2.y;  sy[3]=r2.z;  sz[3]=r2.w;
        sx[4]=r3.x;  sy[4]=r3.y;  sz[4]=r3.z;
        sx[5]=r3.w;  sy[5]=r4v.x; sz[5]=r4v.y;
        sx[6]=r4v.z; sy[6]=r4v.w; sz[6]=r5.x;
        sx[7]=r5.y;  sy[7]=r5.z;  sz[7]=r5.w;
    } else {
        // Partial-wave lanes: clamp + zero weight (contribute 0 to last ray).
        #pragma unroll
        for (int k = 0; k < SPL; ++k) {
            long long s  = base + k;
            bool      ok = (s < n);
            long long sc = ok ? s : (long long)(n - 1);
            ids[k] = idx[sc];
            ws[k]  = ok ? w[sc] : 0.0f;
            sx[k] = rgb[3*sc+0]; sy[k] = rgb[3*sc+1]; sz[k] = rgb[3*sc+2];
        }
    }

    // ---- Serial in-lane pass: head piece H, interior segs (atomic), tail T.
    const int first = ids[0];
    int   cur = first;
    float ax = ws[0]*sx[0], ay = ws[0]*sy[0], az = ws[0]*sz[0];
    float hx = 0.f, hy = 0.f, hz = 0.f;
    bool  f = false;                     // lane chunk contains a boundary
    #pragma unroll
    for (int k = 1; k < SPL; ++k) {
        if (ids[k] != cur) {
            if (!f) { hx = ax; hy = ay; hz = az; f = true; }
            else {                       // complete interior segment (rare)
                atomicAdd(&out[cur*3+0], ax);
                atomicAdd(&out[cur*3+1], ay);
                atomicAdd(&out[cur*3+2], az);
            }
            ax = ay = az = 0.f;
            cur = ids[k];
        }
        ax = fmaf(ws[k], sx[k], ax);
        ay = fmaf(ws[k], sy[k], ay);
        az = fmaf(ws[k], sz[k], az);
    }
    const int t_id = cur;                // tail piece (ax,ay,az) belongs here

    // ---- Cross-lane segmented suffix scan over tail pieces.
    int  t_prev = __shfl_up(t_id, 1);
    bool brk    = f || (lane > 0 && t_prev != first);  // segment break at left edge
    unsigned long long bm = __ballot(brk);

    float Sx = ax, Sy = ay, Sz = az;
    #pragma unroll
    for (int d = 1; d < 64; d <<= 1) {
        float ox = __shfl_down(Sx, d);
        float oy = __shfl_down(Sy, d);
        float oz = __shfl_down(Sz, d);
        // merge lane+d iff no break flag in lanes (lane, lane+d]
        unsigned long long between = ((bm >> 1) >> lane) & ((1ull << d) - 1ull);
        bool cont = (lane + d < 64) && (between == 0);
        if (cont) { Sx += ox; Sy += oy; Sz += oz; }
    }

    if (lane == 0 || brk) {              // scan head: flush merged tail run
        atomicAdd(&out[t_id*3+0], Sx);
        atomicAdd(&out[t_id*3+1], Sy);
        atomicAdd(&out[t_id*3+2], Sz);
    }
    if (f) {                             // head piece closes the previous run
        atomicAdd(&out[first*3+0], hx);
        atomicAdd(&out[first*3+1], hy);
        atomicAdd(&out[first*3+2], hz);
    }
}

extern "C" void kernel_launch(void* const* d_in, const int* in_sizes, int n_in,
                              void* d_out, int out_size, void* d_ws, size_t ws_size,
                              hipStream_t stream) {
    const float* rgb = (const float*)d_in[0];   // [n,3] f32
    const float* w   = (const float*)d_in[1];   // [n,1] f32
    const int*   idx = (const int*)  d_in[2];   // [n]   i32 sorted
    float*       out = (float*)d_out;           // [n_rays,3] f32

    int n = in_sizes[2];

    // Output is re-poisoned to 0xAA before every timed launch — zero it.
    hipMemsetAsync(d_out, 0, (size_t)out_size * sizeof(float), stream);

    long long waves  = ((long long)n + WAVE_SAMPLES - 1) / WAVE_SAMPLES;
    long long blocks = (waves + 3) / 4;          // 4 waves (256 threads) / block
    integrate_kernel<<<(int)blocks, 256, 0, stream>>>(rgb, w, idx, out, n);
}

// Round 4
// 110.005 us; speedup vs baseline: 1.0121x; 1.0121x over previous
//
#include <hip/hip_runtime.h>

// Segmented (per-ray) weighted RGB sum over SORTED ray_indices.
// R4: single-generation streaming. 1024 blocks x 256 = 4096 waves = 16/CU,
// all co-resident. Each wave owns TPW=2 consecutive 512-sample tiles and
// issues ALL loads up front (20 x 16B vector loads/lane) before reducing,
// so each CU demands its full byte budget immediately and HBM streams at
// line rate. Reduce = per-lane serial FMA over 8 contiguous samples + one
// wave-level segmented suffix scan per tile; only run boundaries atomicAdd.

#define SPL 8                    // contiguous samples per lane
#define WAVE_SAMPLES (64 * SPL)  // 512 samples per tile
#define TPW 2                    // tiles per wave

struct Tile {
    int   ids[SPL];
    float ws[SPL], sx[SPL], sy[SPL], sz[SPL];
};

__device__ __forceinline__ void load_tile(const float* __restrict__ rgb,
                                          const float* __restrict__ w,
                                          const int*   __restrict__ idx,
                                          long long tbase, int lane, int n,
                                          Tile& T)
{
    const long long base = tbase + (long long)lane * SPL;
    if (base + SPL <= n) {
        int4   i0 = *(const int4*)(idx + base);
        int4   i1 = *(const int4*)(idx + base + 4);
        float4 w0 = *(const float4*)(w + base);
        float4 w1 = *(const float4*)(w + base + 4);
        const float4* r4 = (const float4*)(rgb + 3 * base);
        float4 r0 = r4[0], r1 = r4[1], r2 = r4[2];
        float4 r3 = r4[3], r4v = r4[4], r5 = r4[5];

        T.ids[0]=i0.x; T.ids[1]=i0.y; T.ids[2]=i0.z; T.ids[3]=i0.w;
        T.ids[4]=i1.x; T.ids[5]=i1.y; T.ids[6]=i1.z; T.ids[7]=i1.w;
        T.ws[0]=w0.x; T.ws[1]=w0.y; T.ws[2]=w0.z; T.ws[3]=w0.w;
        T.ws[4]=w1.x; T.ws[5]=w1.y; T.ws[6]=w1.z; T.ws[7]=w1.w;
        T.sx[0]=r0.x;  T.sy[0]=r0.y;  T.sz[0]=r0.z;
        T.sx[1]=r0.w;  T.sy[1]=r1.x;  T.sz[1]=r1.y;
        T.sx[2]=r1.z;  T.sy[2]=r1.w;  T.sz[2]=r2.x;
        T.sx[3]=r2.y;  T.sy[3]=r2.z;  T.sz[3]=r2.w;
        T.sx[4]=r3.x;  T.sy[4]=r3.y;  T.sz[4]=r3.z;
        T.sx[5]=r3.w;  T.sy[5]=r4v.x; T.sz[5]=r4v.y;
        T.sx[6]=r4v.z; T.sy[6]=r4v.w; T.sz[6]=r5.x;
        T.sx[7]=r5.y;  T.sy[7]=r5.z;  T.sz[7]=r5.w;
    } else {
        #pragma unroll
        for (int k = 0; k < SPL; ++k) {
            long long s  = base + k;
            bool      ok = (s < n);
            long long sc = ok ? s : (long long)(n - 1);
            T.ids[k] = idx[sc];
            T.ws[k]  = ok ? w[sc] : 0.0f;
            T.sx[k] = rgb[3*sc+0]; T.sy[k] = rgb[3*sc+1]; T.sz[k] = rgb[3*sc+2];
        }
    }
}

__device__ __forceinline__ void process_tile(const Tile& T, int lane,
                                             float* __restrict__ out)
{
    // Serial in-lane pass: head piece H, interior complete segs (atomic), tail.
    const int first = T.ids[0];
    int   cur = first;
    float ax = T.ws[0]*T.sx[0], ay = T.ws[0]*T.sy[0], az = T.ws[0]*T.sz[0];
    float hx = 0.f, hy = 0.f, hz = 0.f;
    bool  f = false;                     // boundary inside this lane's chunk
    #pragma unroll
    for (int k = 1; k < SPL; ++k) {
        if (T.ids[k] != cur) {
            if (!f) { hx = ax; hy = ay; hz = az; f = true; }
            else {
                atomicAdd(&out[cur*3+0], ax);
                atomicAdd(&out[cur*3+1], ay);
                atomicAdd(&out[cur*3+2], az);
            }
            ax = ay = az = 0.f;
            cur = T.ids[k];
        }
        ax = fmaf(T.ws[k], T.sx[k], ax);
        ay = fmaf(T.ws[k], T.sy[k], ay);
        az = fmaf(T.ws[k], T.sz[k], az);
    }
    const int t_id = cur;

    // Cross-lane segmented suffix scan over per-lane tail pieces.
    int  t_prev = __shfl_up(t_id, 1);
    bool brk    = f || (lane > 0 && t_prev != first);
    unsigned long long bm = __ballot(brk);

    float Sx = ax, Sy = ay, Sz = az;
    #pragma unroll
    for (int d = 1; d < 64; d <<= 1) {
        float ox = __shfl_down(Sx, d);
        float oy = __shfl_down(Sy, d);
        float oz = __shfl_down(Sz, d);
        unsigned long long between = ((bm >> 1) >> lane) & ((1ull << d) - 1ull);
        bool cont = (lane + d < 64) && (between == 0);
        if (cont) { Sx += ox; Sy += oy; Sz += oz; }
    }

    if (lane == 0 || brk) {
        atomicAdd(&out[t_id*3+0], Sx);
        atomicAdd(&out[t_id*3+1], Sy);
        atomicAdd(&out[t_id*3+2], Sz);
    }
    if (f) {
        atomicAdd(&out[first*3+0], hx);
        atomicAdd(&out[first*3+1], hy);
        atomicAdd(&out[first*3+2], hz);
    }
}

__global__ __launch_bounds__(256, 4) void integrate_kernel(
    const float* __restrict__ rgb,      // [n, 3]
    const float* __restrict__ w,        // [n, 1]
    const int*   __restrict__ idx,      // [n] sorted
    float*       __restrict__ out,      // [n_rays, 3], pre-zeroed
    int n)
{
    const int lane = threadIdx.x & 63;
    const long long wave = ((long long)blockIdx.x * blockDim.x + threadIdx.x) >> 6;
    const long long b0 = wave * (TPW * (long long)WAVE_SAMPLES);
    if (b0 >= n) return;                 // wave-uniform exit
    const long long b1 = b0 + WAVE_SAMPLES;

    // Issue ALL loads before any reduction (max MLP; __restrict__ lets the
    // compiler keep tile-1 loads above tile-0's atomics).
    Tile T0, T1;
    const bool has1 = (b1 < n);
    load_tile(rgb, w, idx, b0, lane, n, T0);
    if (has1) load_tile(rgb, w, idx, b1, lane, n, T1);

    process_tile(T0, lane, out);
    if (has1) process_tile(T1, lane, out);
}

extern "C" void kernel_launch(void* const* d_in, const int* in_sizes, int n_in,
                              void* d_out, int out_size, void* d_ws, size_t ws_size,
                              hipStream_t stream) {
    const float* rgb = (const float*)d_in[0];   // [n,3] f32
    const float* w   = (const float*)d_in[1];   // [n,1] f32
    const int*   idx = (const int*)  d_in[2];   // [n]   i32 sorted
    float*       out = (float*)d_out;           // [n_rays,3] f32

    int n = in_sizes[2];

    // Output is re-poisoned to 0xAA before every timed launch — zero it.
    hipMemsetAsync(d_out, 0, (size_t)out_size * sizeof(float), stream);

    long long tiles  = ((long long)n + WAVE_SAMPLES - 1) / WAVE_SAMPLES;
    long long waves  = (tiles + TPW - 1) / TPW;
    long long blocks = (waves + 3) / 4;          // 4 waves (256 thr) per block
    integrate_kernel<<<(int)blocks, 256, 0, stream>>>(rgb, w, idx, out, n);
}